// Round 14
// baseline (55.824 us; speedup 1.0000x reference)
//
#include <hip/hip_runtime.h>
#include <math.h>
#include <stdint.h>

#define NROWS 1024
#define DCAT  16384
#define NNEG  48
#define CCAP  28    // per-chunk cap: lambda=4, P(Poisson>28)*32768 ~ 3e-10
#define PCAP  8     // exactly 8 positives per row
// Candidate threshold on the 32-bit threefry output: P(pass) = 2^-7 exactly
// -> lambda = 128 cands/row; Chernoff P(row < 48) ~ 2e-15 * 1024 rows ~ 0.
#define BITS_THR 0xFE000000u

typedef unsigned long long ull;

// ws layout (~3.7 MB): 32768 chunk-segments of 512 consecutive elems.
// NO zero-init needed: all consumed fields written unconditionally
// (out[0] is zeroed by scan_kernel, which precedes select in stream order).
//   ccnt u32[32768]      @ 0x000000 (128KB)
//   cand u32[32768][28]  @ 0x020000 (3.5MB)  key: cand=(bits&~0x1FF)|idx9,
//                                            pos-marker=0x200|idx9 (<0x400)
#define WS_CCNT(ws) ((uint32_t*)(ws))
#define WS_CAND(ws) ((uint32_t*)((char*)(ws) + 0x20000))

// ---- Inline-asm threefry2x32, key=(0,42), counter=(0,idx), out=x0^x1
// (jax_threefry_partitionable 32-bit path; R7-R13 verified absmax=0).
// 8 chains operation-interleaved; result lands in x1 regs %8-%15.
#define ADD8 \
  "v_add_u32 %0, %0, %8\n\t"   "v_add_u32 %1, %1, %9\n\t" \
  "v_add_u32 %2, %2, %10\n\t"  "v_add_u32 %3, %3, %11\n\t" \
  "v_add_u32 %4, %4, %12\n\t"  "v_add_u32 %5, %5, %13\n\t" \
  "v_add_u32 %6, %6, %14\n\t"  "v_add_u32 %7, %7, %15\n\t"
#define ADD8_3(K) \
  "v_add3_u32 %0, %0, %8, " K "\n\t"   "v_add3_u32 %1, %1, %9, " K "\n\t" \
  "v_add3_u32 %2, %2, %10, " K "\n\t"  "v_add3_u32 %3, %3, %11, " K "\n\t" \
  "v_add3_u32 %4, %4, %12, " K "\n\t"  "v_add3_u32 %5, %5, %13, " K "\n\t" \
  "v_add3_u32 %6, %6, %14, " K "\n\t"  "v_add3_u32 %7, %7, %15, " K "\n\t"
#define ROT8(SH) \
  "v_alignbit_b32 %8, %8, %8, " SH "\n\t"   "v_alignbit_b32 %9, %9, %9, " SH "\n\t" \
  "v_alignbit_b32 %10, %10, %10, " SH "\n\t" "v_alignbit_b32 %11, %11, %11, " SH "\n\t" \
  "v_alignbit_b32 %12, %12, %12, " SH "\n\t" "v_alignbit_b32 %13, %13, %13, " SH "\n\t" \
  "v_alignbit_b32 %14, %14, %14, " SH "\n\t" "v_alignbit_b32 %15, %15, %15, " SH "\n\t"
#define XOR8 \
  "v_xor_b32 %8, %8, %0\n\t"   "v_xor_b32 %9, %9, %1\n\t" \
  "v_xor_b32 %10, %10, %2\n\t" "v_xor_b32 %11, %11, %3\n\t" \
  "v_xor_b32 %12, %12, %4\n\t" "v_xor_b32 %13, %13, %5\n\t" \
  "v_xor_b32 %14, %14, %6\n\t" "v_xor_b32 %15, %15, %7\n\t"
#define INJ1(K) \
  "v_add_u32 %8, " K ", %8\n\t"  "v_add_u32 %9, " K ", %9\n\t" \
  "v_add_u32 %10, " K ", %10\n\t" "v_add_u32 %11, " K ", %11\n\t" \
  "v_add_u32 %12, " K ", %12\n\t" "v_add_u32 %13, " K ", %13\n\t" \
  "v_add_u32 %14, " K ", %14\n\t" "v_add_u32 %15, " K ", %15\n\t"
#define INJ0S \
  "v_add_u32 %0, %16, %0\n\t" "v_add_u32 %1, %16, %1\n\t" \
  "v_add_u32 %2, %16, %2\n\t" "v_add_u32 %3, %16, %3\n\t" \
  "v_add_u32 %4, %16, %4\n\t" "v_add_u32 %5, %16, %5\n\t" \
  "v_add_u32 %6, %16, %6\n\t" "v_add_u32 %7, %16, %7\n\t"
#define TF8_ASM \
  asm(ROT8("19") XOR8                                  \
      ADD8 ROT8("17") XOR8                             \
      ADD8 ROT8("6")  XOR8                             \
      ADD8 ROT8("26") XOR8 INJ1("%17")                 \
      ADD8_3("42") ROT8("15") XOR8                     \
      ADD8 ROT8("3")  XOR8                             \
      ADD8 ROT8("16") XOR8                             \
      ADD8 ROT8("8")  XOR8 INJ1("2")                   \
      ADD8_3("%16") ROT8("19") XOR8                    \
      ADD8 ROT8("17") XOR8                             \
      ADD8 ROT8("6")  XOR8                             \
      ADD8 ROT8("26") XOR8 INJ1("45")                  \
      ADD8 ROT8("15") XOR8                             \
      ADD8 ROT8("3")  XOR8                             \
      ADD8 ROT8("16") XOR8                             \
      ADD8 ROT8("8")  XOR8 INJ1("%18")                 \
      ADD8_3("42") ROT8("19") XOR8                     \
      ADD8 ROT8("17") XOR8                             \
      ADD8 ROT8("6")  XOR8                             \
      ADD8 ROT8("26") XOR8 INJ0S INJ1("5") XOR8        \
      : "+v"(x00),"+v"(x01),"+v"(x02),"+v"(x03),       \
        "+v"(x04),"+v"(x05),"+v"(x06),"+v"(x07),       \
        "+v"(x10),"+v"(x11),"+v"(x12),"+v"(x13),       \
        "+v"(x14),"+v"(x15),"+v"(x16),"+v"(x17)        \
      : "s"(kA), "s"(kB), "s"(kC))

__device__ __forceinline__ uint32_t mbcnt64_(ull m) {
  return __builtin_amdgcn_mbcnt_hi((uint32_t)(m >> 32),
                                   __builtin_amdgcn_mbcnt_lo((uint32_t)m, 0));
}

// jax.nn.softplus = max(x,0) + log1p(exp(-|x|))
__device__ __forceinline__ float softplus_(float x) {
  return fmaxf(x, 0.f) + log1pf(expf(-fabsf(x)));
}

// ---- Kernel A: barrier/LDS/atomic-free threefry scan.
// 8192 blocks x 256 thr; thread = 8 elems; wave = 512-elem chunk owning a
// fixed global segment. ONE merged ballot per element; positives push
// markers, never candidate keys. Block 0 also zeroes out[0] (stream order
// guarantees this lands before select's atomics).
__global__ __launch_bounds__(256) void scan_kernel(
    const float* __restrict__ target, void* __restrict__ ws,
    float* __restrict__ out) {
  const int tid = threadIdx.x;
  const int lane = tid & 63;
  if (blockIdx.x == 0 && tid == 0) out[0] = 0.f;
  const uint32_t e0 = ((uint32_t)blockIdx.x << 11) | ((uint32_t)tid << 3);
  const uint32_t w  = ((uint32_t)blockIdx.x << 2) | ((uint32_t)tid >> 6);
  const uint32_t kA = 0x1BD11BF0u, kB = 0x1BD11BF1u, kC = 0x1BD11BF4u;
  const uint32_t l3 = (uint32_t)(lane << 3);

  // target preload (latency hides under the ~560-instr asm block)
  const float4 a0 = *reinterpret_cast<const float4*>(target + e0);
  const float4 a1 = *reinterpret_cast<const float4*>(target + e0 + 4);

  uint32_t x00=e0+42u,x01=e0+43u,x02=e0+44u,x03=e0+45u;
  uint32_t x04=e0+46u,x05=e0+47u,x06=e0+48u,x07=e0+49u;
  uint32_t x10=x00,x11=x01,x12=x02,x13=x03,x14=x04,x15=x05,x16=x06,x17=x07;
  TF8_ASM;
  const uint32_t b[8] = {x10,x11,x12,x13,x14,x15,x16,x17};
  const float tv[8] = {a0.x, a0.y, a0.z, a0.w, a1.x, a1.y, a1.z, a1.w};

  uint32_t* __restrict__ cseg = WS_CAND(ws) + w * CCAP;
  uint32_t wc = 0;
  #pragma unroll
  for (int j = 0; j < 8; ++j) {
    const bool pos  = tv[j] > 0.f;                 // exactly 8/row
    const bool hit  = pos | (b[j] >= BITS_THR);    // ~0.83%/elem
    const ull m = __ballot(hit);
    if (m) {                                       // ~39% of wave-slots
      const uint32_t slot = wc + mbcnt64_(m);
      if (hit && slot < CCAP)
        cseg[slot] = pos ? (0x200u | l3 | (uint32_t)j)
                         : ((b[j] & 0xFFFFFE00u) | l3 | (uint32_t)j);
      wc += (uint32_t)__popcll(m);
    }
  }
  if (lane == 0) WS_CCNT(ws)[w] = wc < CCAP ? wc : CCAP;
}

// ---- Kernel B: per-row selection + loss -> one atomicAdd per block into
// out[0] (zeroed by scan each call; 1024 atomics total, negligible).
__global__ __launch_bounds__(256) void select_kernel(
    const float* __restrict__ pred, void* __restrict__ ws,
    float* __restrict__ out) {
  const int row = blockIdx.x;
  const int tid = threadIdx.x;
  const uint32_t w0 = (uint32_t)row << 5;       // 32 chunk-segments per row
  const float* __restrict__ prow = pred + (size_t)row * DCAT;

  __shared__ ull dense[32 * CCAP];              // 896 * 8B = 7KB
  __shared__ int pos_s[PCAP];
  __shared__ int pn_s, mn_s;
  __shared__ float wsum[4];
  if (tid < PCAP) pos_s[tid] = -1;
  if (tid == 0) { pn_s = 0; mn_s = 0; }
  __syncthreads();

  // classify + compact (rank-count below is order-independent, so LDS
  // atomic compaction order doesn't affect the selected set):
  // 32 segments, 8 threads each; expand cand u32 -> u64 (rank desc, col asc)
  {
    const int g = tid >> 3, l = tid & 7;
    const uint32_t cw0 = WS_CCNT(ws)[w0 + g];
    const uint32_t cw = cw0 < CCAP ? cw0 : CCAP;
    const uint32_t cbase = ((uint32_t)g) << 9;  // col base within row
    for (uint32_t s = l; s < cw; s += 8) {
      const uint32_t k = WS_CAND(ws)[(w0 + g) * CCAP + s];
      const uint32_t col = cbase + (k & 0x1FFu);
      if (k < 0x400u) {                         // positive marker
        const int p = atomicAdd(&pn_s, 1);
        if (p < PCAP) pos_s[p] = (int)col;
      } else {                                  // negative candidate
        const int d = atomicAdd(&mn_s, 1);
        dense[d] = ((ull)(k >> 9) << 14) | (ull)(DCAT - 1 - col);
      }
    }
  }
  __syncthreads();

  float acc = 0.f;
  // exact top-48 by rank-counting (O(M^2), M~128, broadcast LDS reads,
  // order-independent -> deterministic) + negative loss
  const int M = mn_s;
  for (int i = tid; i < M; i += 256) {
    const ull mine = dense[i];
    int higher = 0;
    for (int j = 0; j < M; ++j) higher += (dense[j] > mine) ? 1 : 0;
    if (higher < NNEG) {
      const int col = DCAT - 1 - (int)(mine & 0x3FFFull);
      acc += softplus_(prow[col]);              // negative term: softplus(x)
    }
  }
  // positive loss (exactly K=8 per row)
  if (tid < PCAP && pos_s[tid] >= 0) acc += softplus_(-prow[pos_s[tid]]);

  // block reduction -> one global atomic per block
  for (int o = 32; o > 0; o >>= 1) acc += __shfl_down(acc, o, 64);
  if ((tid & 63) == 0) wsum[tid >> 6] = acc;
  __syncthreads();
  if (tid == 0)
    atomicAdd(out, wsum[0] + wsum[1] + wsum[2] + wsum[3]);
}

extern "C" void kernel_launch(void* const* d_in, const int* in_sizes, int n_in,
                              void* d_out, int out_size, void* d_ws, size_t ws_size,
                              hipStream_t stream) {
  const float* pred   = (const float*)d_in[0];
  const float* target = (const float*)d_in[1];
  // d_in[2] = k (int scalar) — compile-time constant 8 in this problem.
  float* out = (float*)d_out;
  // NO memsets: ws fields written unconditionally; out[0] zeroed by scan.
  scan_kernel<<<dim3(NROWS * 8), dim3(256), 0, stream>>>(target, d_ws, out);
  select_kernel<<<dim3(NROWS), dim3(256), 0, stream>>>(pred, d_ws, out);
}

// Round 15
// 45.740 us; speedup vs baseline: 1.2205x; 1.2205x over previous
//
#include <hip/hip_runtime.h>
#include <math.h>
#include <stdint.h>

#define NROWS 1024
#define DCAT  16384
#define NNEG  48
#define CCAP  28    // per-chunk cap: lambda=4, P(Poisson>28)*32768 ~ 3e-10
#define PCAP  8     // exactly 8 positives per row
// Candidate threshold on the 32-bit threefry output: P(pass) = 2^-7 exactly
// -> lambda = 128 cands/row; Chernoff P(row < 48) ~ 2e-15 * 1024 rows ~ 0.
#define BITS_THR 0xFE000000u

typedef unsigned long long ull;

// ws layout (~3.7 MB): 32768 chunk-segments of 512 consecutive elems.
// NO zero-init needed: all consumed fields written unconditionally.
//   ccnt u32[32768]      @ 0x000000 (128KB)
//   cand u32[32768][28]  @ 0x020000 (3.5MB)  key: cand=(bits&~0x1FF)|idx9,
//                                            pos-marker=0x200|idx9 (<0x400)
//   part f32[1024]       @ 0x3A0000 (4KB)
#define WS_CCNT(ws) ((uint32_t*)(ws))
#define WS_CAND(ws) ((uint32_t*)((char*)(ws) + 0x20000))
#define WS_PART(ws) ((float*)((char*)(ws) + 0x3A0000))

// ---- Inline-asm threefry2x32, key=(0,42), counter=(0,idx), out=x0^x1
// (jax_threefry_partitionable 32-bit path; R7-R14 verified absmax=0).
// 8 chains operation-interleaved; result lands in x1 regs %8-%15.
#define ADD8 \
  "v_add_u32 %0, %0, %8\n\t"   "v_add_u32 %1, %1, %9\n\t" \
  "v_add_u32 %2, %2, %10\n\t"  "v_add_u32 %3, %3, %11\n\t" \
  "v_add_u32 %4, %4, %12\n\t"  "v_add_u32 %5, %5, %13\n\t" \
  "v_add_u32 %6, %6, %14\n\t"  "v_add_u32 %7, %7, %15\n\t"
#define ADD8_3(K) \
  "v_add3_u32 %0, %0, %8, " K "\n\t"   "v_add3_u32 %1, %1, %9, " K "\n\t" \
  "v_add3_u32 %2, %2, %10, " K "\n\t"  "v_add3_u32 %3, %3, %11, " K "\n\t" \
  "v_add3_u32 %4, %4, %12, " K "\n\t"  "v_add3_u32 %5, %5, %13, " K "\n\t" \
  "v_add3_u32 %6, %6, %14, " K "\n\t"  "v_add3_u32 %7, %7, %15, " K "\n\t"
#define ROT8(SH) \
  "v_alignbit_b32 %8, %8, %8, " SH "\n\t"   "v_alignbit_b32 %9, %9, %9, " SH "\n\t" \
  "v_alignbit_b32 %10, %10, %10, " SH "\n\t" "v_alignbit_b32 %11, %11, %11, " SH "\n\t" \
  "v_alignbit_b32 %12, %12, %12, " SH "\n\t" "v_alignbit_b32 %13, %13, %13, " SH "\n\t" \
  "v_alignbit_b32 %14, %14, %14, " SH "\n\t" "v_alignbit_b32 %15, %15, %15, " SH "\n\t"
#define XOR8 \
  "v_xor_b32 %8, %8, %0\n\t"   "v_xor_b32 %9, %9, %1\n\t" \
  "v_xor_b32 %10, %10, %2\n\t" "v_xor_b32 %11, %11, %3\n\t" \
  "v_xor_b32 %12, %12, %4\n\t" "v_xor_b32 %13, %13, %5\n\t" \
  "v_xor_b32 %14, %14, %6\n\t" "v_xor_b32 %15, %15, %7\n\t"
#define INJ1(K) \
  "v_add_u32 %8, " K ", %8\n\t"  "v_add_u32 %9, " K ", %9\n\t" \
  "v_add_u32 %10, " K ", %10\n\t" "v_add_u32 %11, " K ", %11\n\t" \
  "v_add_u32 %12, " K ", %12\n\t" "v_add_u32 %13, " K ", %13\n\t" \
  "v_add_u32 %14, " K ", %14\n\t" "v_add_u32 %15, " K ", %15\n\t"
#define INJ0S \
  "v_add_u32 %0, %16, %0\n\t" "v_add_u32 %1, %16, %1\n\t" \
  "v_add_u32 %2, %16, %2\n\t" "v_add_u32 %3, %16, %3\n\t" \
  "v_add_u32 %4, %16, %4\n\t" "v_add_u32 %5, %16, %5\n\t" \
  "v_add_u32 %6, %16, %6\n\t" "v_add_u32 %7, %16, %7\n\t"
#define TF8_ASM \
  asm(ROT8("19") XOR8                                  \
      ADD8 ROT8("17") XOR8                             \
      ADD8 ROT8("6")  XOR8                             \
      ADD8 ROT8("26") XOR8 INJ1("%17")                 \
      ADD8_3("42") ROT8("15") XOR8                     \
      ADD8 ROT8("3")  XOR8                             \
      ADD8 ROT8("16") XOR8                             \
      ADD8 ROT8("8")  XOR8 INJ1("2")                   \
      ADD8_3("%16") ROT8("19") XOR8                    \
      ADD8 ROT8("17") XOR8                             \
      ADD8 ROT8("6")  XOR8                             \
      ADD8 ROT8("26") XOR8 INJ1("45")                  \
      ADD8 ROT8("15") XOR8                             \
      ADD8 ROT8("3")  XOR8                             \
      ADD8 ROT8("16") XOR8                             \
      ADD8 ROT8("8")  XOR8 INJ1("%18")                 \
      ADD8_3("42") ROT8("19") XOR8                     \
      ADD8 ROT8("17") XOR8                             \
      ADD8 ROT8("6")  XOR8                             \
      ADD8 ROT8("26") XOR8 INJ0S INJ1("5") XOR8        \
      : "+v"(x00),"+v"(x01),"+v"(x02),"+v"(x03),       \
        "+v"(x04),"+v"(x05),"+v"(x06),"+v"(x07),       \
        "+v"(x10),"+v"(x11),"+v"(x12),"+v"(x13),       \
        "+v"(x14),"+v"(x15),"+v"(x16),"+v"(x17)        \
      : "s"(kA), "s"(kB), "s"(kC))

__device__ __forceinline__ uint32_t mbcnt64_(ull m) {
  return __builtin_amdgcn_mbcnt_hi((uint32_t)(m >> 32),
                                   __builtin_amdgcn_mbcnt_lo((uint32_t)m, 0));
}

// jax.nn.softplus = max(x,0) + log1p(exp(-|x|))
__device__ __forceinline__ float softplus_(float x) {
  return fmaxf(x, 0.f) + log1pf(expf(-fabsf(x)));
}

// ---- Kernel A: barrier/LDS/atomic-free threefry scan.
// 8192 blocks x 256 thr; thread = 8 elems; wave = 512-elem chunk owning a
// fixed global segment. ONE merged ballot per element; positives push
// markers, never candidate keys -> select needs no masking pass.
__global__ __launch_bounds__(256) void scan_kernel(
    const float* __restrict__ target, void* __restrict__ ws) {
  const int tid = threadIdx.x;
  const int lane = tid & 63;
  const uint32_t e0 = ((uint32_t)blockIdx.x << 11) | ((uint32_t)tid << 3);
  const uint32_t w  = ((uint32_t)blockIdx.x << 2) | ((uint32_t)tid >> 6);
  const uint32_t kA = 0x1BD11BF0u, kB = 0x1BD11BF1u, kC = 0x1BD11BF4u;
  const uint32_t l3 = (uint32_t)(lane << 3);

  // target preload (latency hides under the ~560-instr asm block)
  const float4 a0 = *reinterpret_cast<const float4*>(target + e0);
  const float4 a1 = *reinterpret_cast<const float4*>(target + e0 + 4);

  uint32_t x00=e0+42u,x01=e0+43u,x02=e0+44u,x03=e0+45u;
  uint32_t x04=e0+46u,x05=e0+47u,x06=e0+48u,x07=e0+49u;
  uint32_t x10=x00,x11=x01,x12=x02,x13=x03,x14=x04,x15=x05,x16=x06,x17=x07;
  TF8_ASM;
  const uint32_t b[8] = {x10,x11,x12,x13,x14,x15,x16,x17};
  const float tv[8] = {a0.x, a0.y, a0.z, a0.w, a1.x, a1.y, a1.z, a1.w};

  uint32_t* __restrict__ cseg = WS_CAND(ws) + w * CCAP;
  uint32_t wc = 0;
  #pragma unroll
  for (int j = 0; j < 8; ++j) {
    const bool pos  = tv[j] > 0.f;                 // exactly 8/row
    const bool hit  = pos | (b[j] >= BITS_THR);    // ~0.83%/elem
    const ull m = __ballot(hit);
    if (m) {                                       // ~39% of wave-slots
      const uint32_t slot = wc + mbcnt64_(m);
      if (hit && slot < CCAP)
        cseg[slot] = pos ? (0x200u | l3 | (uint32_t)j)
                         : ((b[j] & 0xFFFFFE00u) | l3 | (uint32_t)j);
      wc += (uint32_t)__popcll(m);
    }
  }
  if (lane == 0) WS_CCNT(ws)[w] = wc < CCAP ? wc : CCAP;
}

// ---- Kernel B: per-row selection + loss -> partial[row] (plain store).
// Candidate set already excludes positives (marker priority in scan).
__global__ __launch_bounds__(256) void select_kernel(
    const float* __restrict__ pred, void* __restrict__ ws) {
  const int row = blockIdx.x;
  const int tid = threadIdx.x;
  const uint32_t w0 = (uint32_t)row << 5;       // 32 chunk-segments per row
  const float* __restrict__ prow = pred + (size_t)row * DCAT;

  __shared__ ull dense[32 * CCAP];              // 896 * 8B = 7KB
  __shared__ int pos_s[PCAP];
  __shared__ int pn_s, mn_s;
  __shared__ float wsum[4];
  if (tid < PCAP) pos_s[tid] = -1;
  if (tid == 0) { pn_s = 0; mn_s = 0; }
  __syncthreads();

  // classify + compact (rank-count below is order-independent, so LDS
  // atomic compaction order doesn't affect the selected set):
  // 32 segments, 8 threads each; expand cand u32 -> u64 (rank desc, col asc)
  {
    const int g = tid >> 3, l = tid & 7;
    const uint32_t cw0 = WS_CCNT(ws)[w0 + g];
    const uint32_t cw = cw0 < CCAP ? cw0 : CCAP;
    const uint32_t cbase = ((uint32_t)g) << 9;  // col base within row
    for (uint32_t s = l; s < cw; s += 8) {
      const uint32_t k = WS_CAND(ws)[(w0 + g) * CCAP + s];
      const uint32_t col = cbase + (k & 0x1FFu);
      if (k < 0x400u) {                         // positive marker
        const int p = atomicAdd(&pn_s, 1);
        if (p < PCAP) pos_s[p] = (int)col;
      } else {                                  // negative candidate
        const int d = atomicAdd(&mn_s, 1);
        dense[d] = ((ull)(k >> 9) << 14) | (ull)(DCAT - 1 - col);
      }
    }
  }
  __syncthreads();

  float acc = 0.f;
  // exact top-48 by rank-counting (O(M^2), M~128, broadcast LDS reads,
  // order-independent -> deterministic) + negative loss
  const int M = mn_s;
  for (int i = tid; i < M; i += 256) {
    const ull mine = dense[i];
    int higher = 0;
    for (int j = 0; j < M; ++j) higher += (dense[j] > mine) ? 1 : 0;
    if (higher < NNEG) {
      const int col = DCAT - 1 - (int)(mine & 0x3FFFull);
      acc += softplus_(prow[col]);              // negative term: softplus(x)
    }
  }
  // positive loss (exactly K=8 per row)
  if (tid < PCAP && pos_s[tid] >= 0) acc += softplus_(-prow[pos_s[tid]]);

  // block reduction -> unconditional plain store (no atomics, no init)
  for (int o = 32; o > 0; o >>= 1) acc += __shfl_down(acc, o, 64);
  if ((tid & 63) == 0) wsum[tid >> 6] = acc;
  __syncthreads();
  if (tid == 0)
    WS_PART(ws)[row] = wsum[0] + wsum[1] + wsum[2] + wsum[3];
}

// ---- Kernel C: fixed-tree reduction of 1024 partials -> out[0].
__global__ __launch_bounds__(256) void reduce_kernel(
    const void* __restrict__ ws, float* __restrict__ out) {
  const int tid = threadIdx.x;
  __shared__ float wsum[4];
  const float4 p = reinterpret_cast<const float4*>(WS_PART(ws))[tid];
  float acc = (p.x + p.y) + (p.z + p.w);
  for (int o = 32; o > 0; o >>= 1) acc += __shfl_down(acc, o, 64);
  if ((tid & 63) == 0) wsum[tid >> 6] = acc;
  __syncthreads();
  if (tid == 0) out[0] = (wsum[0] + wsum[1]) + (wsum[2] + wsum[3]);
}

extern "C" void kernel_launch(void* const* d_in, const int* in_sizes, int n_in,
                              void* d_out, int out_size, void* d_ws, size_t ws_size,
                              hipStream_t stream) {
  const float* pred   = (const float*)d_in[0];
  const float* target = (const float*)d_in[1];
  // d_in[2] = k (int scalar) — compile-time constant 8 in this problem.
  float* out = (float*)d_out;
  // NO memsets: every consumed ws field is written unconditionally each call.
  scan_kernel<<<dim3(NROWS * 8), dim3(256), 0, stream>>>(target, d_ws);
  select_kernel<<<dim3(NROWS), dim3(256), 0, stream>>>(pred, d_ws);
  reduce_kernel<<<dim3(1), dim3(256), 0, stream>>>(d_ws, out);
}